// Round 2
// baseline (337.390 us; speedup 1.0000x reference)
//
#include <hip/hip_runtime.h>

typedef _Float16 half8_t __attribute__((ext_vector_type(8)));
typedef _Float16 half4_t __attribute__((ext_vector_type(4)));
typedef float    float4_t __attribute__((ext_vector_type(4)));

#define DIM 768
#define BK 32
#define KSTEPS 24   // 768 / 32

// ---------------------------------------------------------------------------
// Generic NT GEMM: out[r][c] = op( sum_k A[r][k] * W[c][k] )   (x @ W.T form)
// A: row-major [M][768] (fp32 or fp16), W: [768][768] fp32 row-major.
// Tile 128x128, BK=32, 256 threads = 4 waves, each wave 64x64 (4x4 MFMA frags).
// ---------------------------------------------------------------------------
template<bool A_HALF, bool OUT_F32, bool ELU, bool BIAS>
__global__ __launch_bounds__(256) void gemm_nt(const void* __restrict__ Av,
                                               const float* __restrict__ W,
                                               const float* __restrict__ bias,
                                               void* __restrict__ Ov)
{
    // 72-halves row stride: 144B, 16B-aligned, <=2-way LDS bank conflict on b128
    __shared__ __align__(16) _Float16 As[128][72];
    __shared__ __align__(16) _Float16 Bs[128][72];

    const int tid  = threadIdx.x;
    const int row0 = blockIdx.y * 128;
    const int col0 = blockIdx.x * 128;
    const int w    = tid >> 6;
    const int lane = tid & 63;
    const int lr   = lane & 15;        // fragment row/col within 16
    const int lkg  = lane >> 4;        // k-group 0..3
    const int wm   = (w & 1) * 64;
    const int wn   = (w >> 1) * 64;

    float4_t acc[4][4] = {};

    for (int ks = 0; ks < KSTEPS; ++ks) {
        const int k0 = ks * BK;
        // ---- stage A tile (128 rows x 32 k) ----
        if (A_HALF) {
            const _Float16* A = (const _Float16*)Av;
            #pragma unroll
            for (int j = 0; j < 2; ++j) {
                int idx = j * 256 + tid;              // 512 half8 slots (128x32)
                int r = idx >> 2, c = (idx & 3) * 8;  // 4 half8 per row
                *(half8_t*)&As[r][c] =
                    *(const half8_t*)&A[(size_t)(row0 + r) * DIM + k0 + c];
            }
        } else {
            const float* A = (const float*)Av;
            #pragma unroll
            for (int j = 0; j < 4; ++j) {
                int idx = j * 256 + tid;              // 1024 float4 slots (128x32)
                int r = idx >> 3, c = (idx & 7) * 4;  // 8 float4 per row
                float4_t f = *(const float4_t*)&A[(size_t)(row0 + r) * DIM + k0 + c];
                half4_t h;
                #pragma unroll
                for (int e = 0; e < 4; ++e) h[e] = (_Float16)f[e];
                *(half4_t*)&As[r][c] = h;
            }
        }
        // ---- stage B tile = W[col0 + r][k0 + c] (always fp32 source) ----
        #pragma unroll
        for (int j = 0; j < 4; ++j) {
            int idx = j * 256 + tid;
            int r = idx >> 3, c = (idx & 7) * 4;
            float4_t f = *(const float4_t*)&W[(size_t)(col0 + r) * DIM + k0 + c];
            half4_t h;
            #pragma unroll
            for (int e = 0; e < 4; ++e) h[e] = (_Float16)f[e];
            *(half4_t*)&Bs[r][c] = h;
        }
        __syncthreads();

        half8_t aF[4], bF[4];
        #pragma unroll
        for (int mi = 0; mi < 4; ++mi)
            aF[mi] = *(const half8_t*)&As[wm + mi * 16 + lr][lkg * 8];
        #pragma unroll
        for (int ni = 0; ni < 4; ++ni)
            bF[ni] = *(const half8_t*)&Bs[wn + ni * 16 + lr][lkg * 8];
        #pragma unroll
        for (int mi = 0; mi < 4; ++mi)
            #pragma unroll
            for (int ni = 0; ni < 4; ++ni)
                acc[mi][ni] = __builtin_amdgcn_mfma_f32_16x16x32_f16(
                    aF[mi], bF[ni], acc[mi][ni], 0, 0, 0);
        __syncthreads();
    }

    // ---- epilogue: C/D layout col = lane&15, row = (lane>>4)*4 + e ----
    #pragma unroll
    for (int mi = 0; mi < 4; ++mi) {
        #pragma unroll
        for (int ni = 0; ni < 4; ++ni) {
            #pragma unroll
            for (int e = 0; e < 4; ++e) {
                int r = row0 + wm + mi * 16 + lkg * 4 + e;
                int c = col0 + wn + ni * 16 + lr;
                float v = acc[mi][ni][e];
                if (ELU) v = (v > 0.0f) ? (v + 1.0f) : __expf(v);  // elu(x)+1
                if (BIAS) v += bias[c];
                if (OUT_F32) ((float*)Ov)[(size_t)r * DIM + c] = v;
                else         ((_Float16*)Ov)[(size_t)r * DIM + c] = (_Float16)v;
            }
        }
    }
}

// ---------------------------------------------------------------------------
// kv_reduce: per (b,h): kvh[e][d] = sum_n v[n,e]*k[n,d];  ksum[d] = sum_n k[n,d]
// grid (8 n-chunks, 96 bh). fp32 atomics accumulate across chunks.
// ---------------------------------------------------------------------------
__global__ __launch_bounds__(256) void kv_reduce(const _Float16* __restrict__ k16,
                                                 const _Float16* __restrict__ v16,
                                                 float* __restrict__ kvh,
                                                 float* __restrict__ ksum)
{
    __shared__ __align__(16) _Float16 K[128][64];
    __shared__ __align__(16) _Float16 V[128][64];
    const int chunk = blockIdx.x;   // 0..7
    const int bh    = blockIdx.y;   // 0..95
    const int b = bh / 12, h = bh % 12;
    const int tid = threadIdx.x;

    const size_t base = ((size_t)b * 1024 + (size_t)chunk * 128) * DIM + h * 64;
    // 128x64 halves = 1024 half8 slots -> j<4  (round-1 fix: was j<2, left
    // columns 32..63 as uninitialized LDS -> NaN)
    #pragma unroll
    for (int j = 0; j < 4; ++j) {
        int idx = j * 256 + tid;              // 1024 half8 slots per matrix
        int r = idx >> 3, c = (idx & 7) * 8;  // 8 half8 per row
        *(half8_t*)&K[r][c] = *(const half8_t*)&k16[base + (size_t)r * DIM + c];
        *(half8_t*)&V[r][c] = *(const half8_t*)&v16[base + (size_t)r * DIM + c];
    }
    __syncthreads();

    const int d0 = (tid & 15) * 4;
    const int e0 = (tid >> 4) * 4;
    float acc[4][4] = {};
    #pragma unroll 4
    for (int n = 0; n < 128; ++n) {
        half4_t kd = *(const half4_t*)&K[n][d0];
        half4_t ve = *(const half4_t*)&V[n][e0];
        #pragma unroll
        for (int i = 0; i < 4; ++i)
            #pragma unroll
            for (int j = 0; j < 4; ++j)
                acc[i][j] += (float)ve[i] * (float)kd[j];
    }
    float* kvp = kvh + (size_t)bh * 64 * 64;
    #pragma unroll
    for (int i = 0; i < 4; ++i)
        #pragma unroll
        for (int j = 0; j < 4; ++j)
            atomicAdd(&kvp[(e0 + i) * 64 + d0 + j], acc[i][j]);

    if (tid < 64) {
        float s = 0.0f;
        for (int n = 0; n < 128; ++n) s += (float)K[n][tid];
        atomicAdd(&ksum[bh * 64 + tid], s);
    }
}

// ---------------------------------------------------------------------------
// attn: per (head, 128-row block): z = 1/(q . ksum + 1e-6); attn = (q @ kv) * z
// q16 layout [32768][768] fp16 (lives in d_out), kvh [bh][e][d] fp32.
// ---------------------------------------------------------------------------
__global__ __launch_bounds__(256) void attn_kernel(const _Float16* __restrict__ q16,
                                                   const float* __restrict__ kvh,
                                                   const float* __restrict__ ksum,
                                                   _Float16* __restrict__ attn16)
{
    __shared__ __align__(16) _Float16 Q[128][72];
    __shared__ __align__(16) _Float16 Bv[64][72];
    __shared__ float S[64];
    __shared__ float Z[128];

    const int h    = blockIdx.x;        // 0..11
    const int rb   = blockIdx.y;        // 0..255
    const int row0 = rb * 128;
    const int b    = row0 >> 12;        // 4096 rows per batch, 128 | 4096
    const int bh   = b * 12 + h;
    const int tid  = threadIdx.x;

    // stage Q head-slice (128 x 64) = 1024 half8 slots -> j<4  (round-1 fix:
    // was j<2, left Q[:,32:64] uninitialized -> NaN)
    #pragma unroll
    for (int j = 0; j < 4; ++j) {
        int idx = j * 256 + tid;
        int r = idx >> 3, c = (idx & 7) * 8;  // 8 half8 per row
        *(half8_t*)&Q[r][c] =
            *(const half8_t*)&q16[(size_t)(row0 + r) * DIM + h * 64 + c];
    }
    // stage kv (64 x 64 fp32 -> fp16), layout Bv[e][d]
    #pragma unroll
    for (int j = 0; j < 4; ++j) {
        int idx = j * 256 + tid;              // 1024 float4 slots
        int r = idx >> 4, c = (idx & 15) * 4; // 16 float4 per row
        float4_t f = *(const float4_t*)&kvh[((size_t)bh * 64 + r) * 64 + c];
        half4_t hh;
        #pragma unroll
        for (int e = 0; e < 4; ++e) hh[e] = (_Float16)f[e];
        *(half4_t*)&Bv[r][c] = hh;
    }
    if (tid < 64) S[tid] = ksum[bh * 64 + tid];
    __syncthreads();

    if (tid < 128) {
        float dot = 0.0f;
        #pragma unroll 8
        for (int d = 0; d < 64; ++d) dot += (float)Q[tid][d] * S[d];
        Z[tid] = 1.0f / (dot + 1e-6f);
    }
    __syncthreads();

    const int w = tid >> 6, lane = tid & 63;
    const int lr = lane & 15, lkg = lane >> 4;
    float4_t acc[2][4] = {};
    #pragma unroll
    for (int kc = 0; kc < 2; ++kc) {
        half8_t aF[2], bF[4];
        #pragma unroll
        for (int mi = 0; mi < 2; ++mi)
            aF[mi] = *(const half8_t*)&Q[w * 32 + mi * 16 + lr][kc * 32 + lkg * 8];
        #pragma unroll
        for (int ni = 0; ni < 4; ++ni)
            bF[ni] = *(const half8_t*)&Bv[ni * 16 + lr][kc * 32 + lkg * 8];
        #pragma unroll
        for (int mi = 0; mi < 2; ++mi)
            #pragma unroll
            for (int ni = 0; ni < 4; ++ni)
                acc[mi][ni] = __builtin_amdgcn_mfma_f32_16x16x32_f16(
                    aF[mi], bF[ni], acc[mi][ni], 0, 0, 0);
    }
    #pragma unroll
    for (int mi = 0; mi < 2; ++mi) {
        #pragma unroll
        for (int ni = 0; ni < 4; ++ni) {
            #pragma unroll
            for (int e = 0; e < 4; ++e) {
                int r = w * 32 + mi * 16 + lkg * 4 + e;
                float v = acc[mi][ni][e] * Z[r];
                attn16[(size_t)(row0 + r) * DIM + h * 64 + ni * 16 + lr] = (_Float16)v;
            }
        }
    }
}

// ---------------------------------------------------------------------------
extern "C" void kernel_launch(void* const* d_in, const int* in_sizes, int n_in,
                              void* d_out, int out_size, void* d_ws, size_t ws_size,
                              hipStream_t stream)
{
    const float* xq  = (const float*)d_in[0];  // [8,4096,768]
    const float* xkv = (const float*)d_in[1];  // [8,1024,768]
    const float* Wq  = (const float*)d_in[2];
    const float* Wk  = (const float*)d_in[3];
    const float* Wv  = (const float*)d_in[4];
    const float* Wo  = (const float*)d_in[5];
    const float* bo  = (const float*)d_in[6];

    char* ws = (char*)d_ws;
    const size_t SZ_KV16 = (size_t)8192 * 768 * 2;   // 12,582,912 B each
    const size_t SZ_ATTN = (size_t)32768 * 768 * 2;  // 50,331,648 B
    const size_t SZ_KVH  = (size_t)96 * 64 * 64 * 4; //  1,572,864 B
    const size_t SZ_KSUM = (size_t)96 * 64 * 4;      //     24,576 B

    _Float16* k16    = (_Float16*)(ws);
    _Float16* v16    = (_Float16*)(ws + SZ_KV16);
    _Float16* attn16 = (_Float16*)(ws + 2 * SZ_KV16);
    float*    kvh    = (float*)   (ws + 2 * SZ_KV16 + SZ_ATTN);
    float*    ksum   = (float*)   (ws + 2 * SZ_KV16 + SZ_ATTN + SZ_KVH);
    // q16 borrows d_out (50MB fp16 inside the 100MB fp32 output buffer);
    // it is fully consumed by attn_kernel before the final GEMM writes d_out.
    _Float16* q16    = (_Float16*)d_out;
    float*    out    = (float*)d_out;

    hipMemsetAsync(kvh, 0, SZ_KVH + SZ_KSUM, stream);

    // k = elu1(x_kv @ Wk.T), v = x_kv @ Wv.T, q = elu1(x_q @ Wq.T)
    gemm_nt<false,false,true ,false><<<dim3(6,  64), 256, 0, stream>>>(xkv, Wk, nullptr, k16);
    gemm_nt<false,false,false,false><<<dim3(6,  64), 256, 0, stream>>>(xkv, Wv, nullptr, v16);
    gemm_nt<false,false,true ,false><<<dim3(6, 256), 256, 0, stream>>>(xq , Wq, nullptr, q16);

    kv_reduce<<<dim3(8, 96), 256, 0, stream>>>(k16, v16, kvh, ksum);
    attn_kernel<<<dim3(12, 256), 256, 0, stream>>>(q16, kvh, ksum, attn16);

    // out = attn @ Wo.T + bo  (fp32 output)
    gemm_nt<true ,true ,false,true ><<<dim3(6, 256), 256, 0, stream>>>(attn16, Wo, bo, out);
}

// Round 3
// 253.785 us; speedup vs baseline: 1.3294x; 1.3294x over previous
//
#include <hip/hip_runtime.h>

typedef _Float16 half8_t __attribute__((ext_vector_type(8)));
typedef _Float16 half4_t __attribute__((ext_vector_type(4)));
typedef float    float4_t __attribute__((ext_vector_type(4)));

#define DIM 768

// async global->LDS, 16B per lane; LDS dest is wave-uniform base + lane*16
#define GLOAD16(g, l) __builtin_amdgcn_global_load_lds(                        \
    (const __attribute__((address_space(1))) void*)(g),                        \
    (__attribute__((address_space(3))) void*)(l), 16, 0, 0)

// ---------------------------------------------------------------------------
// cast helpers
// ---------------------------------------------------------------------------
__global__ __launch_bounds__(256) void cast_f32_f16(const float* __restrict__ s,
                                                    _Float16* __restrict__ d, int n8)
{
    int i = blockIdx.x * 256 + threadIdx.x;
    if (i < n8) {
        float4_t f0 = *(const float4_t*)&s[(size_t)i * 8];
        float4_t f1 = *(const float4_t*)&s[(size_t)i * 8 + 4];
        half8_t h;
        #pragma unroll
        for (int e = 0; e < 4; ++e) { h[e] = (_Float16)f0[e]; h[e + 4] = (_Float16)f1[e]; }
        *(half8_t*)&d[(size_t)i * 8] = h;
    }
}

// casts the four 768x768 weight matrices; blockIdx.y selects tensor
__global__ __launch_bounds__(256) void cast4_f32_f16(
    const float* __restrict__ s0, const float* __restrict__ s1,
    const float* __restrict__ s2, const float* __restrict__ s3,
    _Float16* __restrict__ d0, _Float16* __restrict__ d1,
    _Float16* __restrict__ d2, _Float16* __restrict__ d3)
{
    const float* s; _Float16* d;
    switch (blockIdx.y) {
        case 0: s = s0; d = d0; break;
        case 1: s = s1; d = d1; break;
        case 2: s = s2; d = d2; break;
        default: s = s3; d = d3; break;
    }
    int i = blockIdx.x * 256 + threadIdx.x;   // 288 blocks * 256 = 73728 half8 = 589824
    float4_t f0 = *(const float4_t*)&s[(size_t)i * 8];
    float4_t f1 = *(const float4_t*)&s[(size_t)i * 8 + 4];
    half8_t h;
    #pragma unroll
    for (int e = 0; e < 4; ++e) { h[e] = (_Float16)f0[e]; h[e + 4] = (_Float16)f1[e]; }
    *(half8_t*)&d[(size_t)i * 8] = h;
}

// ---------------------------------------------------------------------------
// m97-structure fp16 NT GEMM: out[r][c] = op( sum_k A[r][k] * W[c][k] )
// A [M][768] fp16, W [768][768] fp16. Tile 128x128, BK=64, 4 waves.
// Linear LDS [128][64], global_load_lds 16B staging, XCD-swizzled 1D grid.
// grid = (M/128)*6 blocks (col-fastest), %8 == 0 for all our shapes.
// ---------------------------------------------------------------------------
template<bool ELU, bool BIAS, bool OUT_F32>
__global__ __launch_bounds__(256) void gemm_h16(const _Float16* __restrict__ A,
                                                const _Float16* __restrict__ W,
                                                const float* __restrict__ bias,
                                                void* __restrict__ Ov)
{
    __shared__ __align__(16) _Float16 As[128 * 64];
    __shared__ __align__(16) _Float16 Bs[128 * 64];

    // XCD-aware bijective swizzle: each XCD gets a contiguous chunk of the
    // col-fastest block order -> one XCD owns each 128-row A panel.
    const int nwg = gridDim.x;
    const int cpx = nwg >> 3;                       // nwg % 8 == 0
    const int bid = (blockIdx.x & 7) * cpx + (blockIdx.x >> 3);
    const int brow = bid / 6;
    const int bcol = bid - brow * 6;
    const int row0 = brow * 128, col0 = bcol * 128;

    const int tid  = threadIdx.x;
    const int w    = tid >> 6, lane = tid & 63;
    const int lr   = lane & 15;          // fragment row/col within 16
    const int lkg  = lane >> 4;          // k-group 0..3
    const int wm   = (w & 1) * 64;
    const int wn   = (w >> 1) * 64;

    // staging: call j stages rows [j*32 + w*8 + lane/8], cols (lane%8)*8..+8
    const int sr = w * 8 + (lane >> 3);
    const int sc = (lane & 7) * 8;
    const _Float16* Ag = A + (size_t)(row0 + sr) * DIM + sc;
    const _Float16* Wg = W + (size_t)(col0 + sr) * DIM + sc;

    float4_t acc[4][4] = {};

    for (int k0 = 0; k0 < DIM; k0 += 64) {
        #pragma unroll
        for (int j = 0; j < 4; ++j)
            GLOAD16(Ag + k0 + j * 32 * DIM, &As[j * 2048 + w * 512]);
        #pragma unroll
        for (int j = 0; j < 4; ++j)
            GLOAD16(Wg + k0 + j * 32 * DIM, &Bs[j * 2048 + w * 512]);
        __syncthreads();   // compiler emits vmcnt(0) lgkmcnt(0) drain here

        half8_t aF[2][4], bF[2][4];
        #pragma unroll
        for (int kk = 0; kk < 2; ++kk) {
            #pragma unroll
            for (int mi = 0; mi < 4; ++mi)
                aF[kk][mi] = *(const half8_t*)&As[(wm + mi * 16 + lr) * 64 + kk * 32 + lkg * 8];
            #pragma unroll
            for (int ni = 0; ni < 4; ++ni)
                bF[kk][ni] = *(const half8_t*)&Bs[(wn + ni * 16 + lr) * 64 + kk * 32 + lkg * 8];
        }
        #pragma unroll
        for (int kk = 0; kk < 2; ++kk)
            #pragma unroll
            for (int mi = 0; mi < 4; ++mi)
                #pragma unroll
                for (int ni = 0; ni < 4; ++ni)
                    acc[mi][ni] = __builtin_amdgcn_mfma_f32_16x16x32_f16(
                        aF[kk][mi], bF[kk][ni], acc[mi][ni], 0, 0, 0);
        __syncthreads();
    }

    // epilogue: C/D layout col = lane&15, row = (lane>>4)*4 + e
    #pragma unroll
    for (int mi = 0; mi < 4; ++mi) {
        #pragma unroll
        for (int ni = 0; ni < 4; ++ni) {
            #pragma unroll
            for (int e = 0; e < 4; ++e) {
                int r = row0 + wm + mi * 16 + lkg * 4 + e;
                int c = col0 + wn + ni * 16 + lr;
                float v = acc[mi][ni][e];
                if (ELU) v = (v > 0.0f) ? (v + 1.0f) : __expf(v);  // elu(x)+1
                if (BIAS) v += bias[c];
                if (OUT_F32) ((float*)Ov)[(size_t)r * DIM + c] = v;
                else         ((_Float16*)Ov)[(size_t)r * DIM + c] = (_Float16)v;
            }
        }
    }
}

// ---------------------------------------------------------------------------
// kv_reduce: per (b,h): kvh[e][d] = sum_n v[n,e]*k[n,d];  ksum[d] = sum_n k[n,d]
// grid (8 n-chunks, 96 bh). fp32 atomics accumulate across chunks.
// ---------------------------------------------------------------------------
__global__ __launch_bounds__(256) void kv_reduce(const _Float16* __restrict__ k16,
                                                 const _Float16* __restrict__ v16,
                                                 float* __restrict__ kvh,
                                                 float* __restrict__ ksum)
{
    __shared__ __align__(16) _Float16 K[128][64];
    __shared__ __align__(16) _Float16 V[128][64];
    const int chunk = blockIdx.x;   // 0..7
    const int bh    = blockIdx.y;   // 0..95
    const int b = bh / 12, h = bh % 12;
    const int tid = threadIdx.x;

    const size_t base = ((size_t)b * 1024 + (size_t)chunk * 128) * DIM + h * 64;
    #pragma unroll
    for (int j = 0; j < 4; ++j) {
        int idx = j * 256 + tid;              // 1024 half8 slots per matrix
        int r = idx >> 3, c = (idx & 7) * 8;  // 8 half8 per row
        *(half8_t*)&K[r][c] = *(const half8_t*)&k16[base + (size_t)r * DIM + c];
        *(half8_t*)&V[r][c] = *(const half8_t*)&v16[base + (size_t)r * DIM + c];
    }
    __syncthreads();

    const int d0 = (tid & 15) * 4;
    const int e0 = (tid >> 4) * 4;
    float acc[4][4] = {};
    #pragma unroll 4
    for (int n = 0; n < 128; ++n) {
        half4_t kd = *(const half4_t*)&K[n][d0];
        half4_t ve = *(const half4_t*)&V[n][e0];
        #pragma unroll
        for (int i = 0; i < 4; ++i)
            #pragma unroll
            for (int j = 0; j < 4; ++j)
                acc[i][j] += (float)ve[i] * (float)kd[j];
    }
    float* kvp = kvh + (size_t)bh * 64 * 64;
    #pragma unroll
    for (int i = 0; i < 4; ++i)
        #pragma unroll
        for (int j = 0; j < 4; ++j)
            atomicAdd(&kvp[(e0 + i) * 64 + d0 + j], acc[i][j]);

    if (tid < 64) {
        float s = 0.0f;
        for (int n = 0; n < 128; ++n) s += (float)K[n][tid];
        atomicAdd(&ksum[bh * 64 + tid], s);
    }
}

// ---------------------------------------------------------------------------
// attn: per (head, 128-row block): z = 1/(q . ksum + 1e-6); attn = (q @ kv) * z
// IN-PLACE on q16: each block reads exactly the region it writes (staged to
// LDS behind a barrier before any store).
// ---------------------------------------------------------------------------
__global__ __launch_bounds__(256) void attn_kernel(_Float16* __restrict__ q16,
                                                   const float* __restrict__ kvh,
                                                   const float* __restrict__ ksum)
{
    __shared__ __align__(16) _Float16 Q[128][72];
    __shared__ __align__(16) _Float16 Bv[64][72];
    __shared__ float S[64];
    __shared__ float Z[128];

    const int h    = blockIdx.x;        // 0..11
    const int rb   = blockIdx.y;        // 0..255
    const int row0 = rb * 128;
    const int b    = row0 >> 12;        // 4096 rows per batch
    const int bh   = b * 12 + h;
    const int tid  = threadIdx.x;

    // stage Q head-slice (128 x 64) = 1024 half8 slots
    #pragma unroll
    for (int j = 0; j < 4; ++j) {
        int idx = j * 256 + tid;
        int r = idx >> 3, c = (idx & 7) * 8;
        *(half8_t*)&Q[r][c] =
            *(const half8_t*)&q16[(size_t)(row0 + r) * DIM + h * 64 + c];
    }
    // stage kv (64 x 64 fp32 -> fp16), layout Bv[e][d]
    #pragma unroll
    for (int j = 0; j < 4; ++j) {
        int idx = j * 256 + tid;              // 1024 float4 slots
        int r = idx >> 4, c = (idx & 15) * 4;
        float4_t f = *(const float4_t*)&kvh[((size_t)bh * 64 + r) * 64 + c];
        half4_t hh;
        #pragma unroll
        for (int e = 0; e < 4; ++e) hh[e] = (_Float16)f[e];
        *(half4_t*)&Bv[r][c] = hh;
    }
    if (tid < 64) S[tid] = ksum[bh * 64 + tid];
    __syncthreads();

    if (tid < 128) {
        float dot = 0.0f;
        #pragma unroll 8
        for (int d = 0; d < 64; ++d) dot += (float)Q[tid][d] * S[d];
        Z[tid] = 1.0f / (dot + 1e-6f);
    }
    __syncthreads();

    const int w = tid >> 6, lane = tid & 63;
    const int lr = lane & 15, lkg = lane >> 4;
    float4_t acc[2][4] = {};
    #pragma unroll
    for (int kc = 0; kc < 2; ++kc) {
        half8_t aF[2], bF[4];
        #pragma unroll
        for (int mi = 0; mi < 2; ++mi)
            aF[mi] = *(const half8_t*)&Q[w * 32 + mi * 16 + lr][kc * 32 + lkg * 8];
        #pragma unroll
        for (int ni = 0; ni < 4; ++ni)
            bF[ni] = *(const half8_t*)&Bv[ni * 16 + lr][kc * 32 + lkg * 8];
        #pragma unroll
        for (int mi = 0; mi < 2; ++mi)
            #pragma unroll
            for (int ni = 0; ni < 4; ++ni)
                acc[mi][ni] = __builtin_amdgcn_mfma_f32_16x16x32_f16(
                    aF[mi], bF[ni], acc[mi][ni], 0, 0, 0);
    }
    #pragma unroll
    for (int mi = 0; mi < 2; ++mi) {
        #pragma unroll
        for (int ni = 0; ni < 4; ++ni) {
            #pragma unroll
            for (int e = 0; e < 4; ++e) {
                int r = w * 32 + mi * 16 + lkg * 4 + e;
                float v = acc[mi][ni][e] * Z[r];
                q16[(size_t)(row0 + r) * DIM + h * 64 + ni * 16 + lr] = (_Float16)v;
            }
        }
    }
}

// ---------------------------------------------------------------------------
extern "C" void kernel_launch(void* const* d_in, const int* in_sizes, int n_in,
                              void* d_out, int out_size, void* d_ws, size_t ws_size,
                              hipStream_t stream)
{
    const float* xq  = (const float*)d_in[0];  // [8,4096,768]
    const float* xkv = (const float*)d_in[1];  // [8,1024,768]
    const float* Wq  = (const float*)d_in[2];
    const float* Wk  = (const float*)d_in[3];
    const float* Wv  = (const float*)d_in[4];
    const float* Wo  = (const float*)d_in[5];
    const float* bo  = (const float*)d_in[6];

    // ---- workspace layout (66.0 MB used) ----
    char* ws = (char*)d_ws;
    const size_t SZ_XKV16 = (size_t)8192 * 768 * 2;    // 12,582,912
    const size_t SZ_Q16   = (size_t)32768 * 768 * 2;   // 50,331,648
    const size_t SZ_W16   = (size_t)768 * 768 * 2;     //  1,179,648
    const size_t SZ_KVH   = (size_t)96 * 64 * 64 * 4;  //  1,572,864
    const size_t SZ_KSUM  = (size_t)96 * 64 * 4;       //     24,576

    _Float16* xkv16 = (_Float16*)(ws);
    _Float16* q16   = (_Float16*)(ws + SZ_XKV16);
    _Float16* Wq16  = (_Float16*)(ws + SZ_XKV16 + SZ_Q16);
    _Float16* Wk16  = (_Float16*)(ws + SZ_XKV16 + SZ_Q16 + SZ_W16);
    _Float16* Wv16  = (_Float16*)(ws + SZ_XKV16 + SZ_Q16 + 2 * SZ_W16);
    _Float16* Wo16  = (_Float16*)(ws + SZ_XKV16 + SZ_Q16 + 3 * SZ_W16);
    float*    kvh   = (float*)   (ws + SZ_XKV16 + SZ_Q16 + 4 * SZ_W16);
    float*    ksum  = (float*)   (ws + SZ_XKV16 + SZ_Q16 + 4 * SZ_W16 + SZ_KVH);

    // ---- d_out aliasing: xq16/k16/v16 live in d_out (100.7 MB fp32) and are
    // fully consumed before the final out-proj GEMM overwrites d_out. ----
    char* ob = (char*)d_out;
    _Float16* xq16 = (_Float16*)(ob);                         // 50,331,648 B
    _Float16* k16  = (_Float16*)(ob + 50331648);              // 12,582,912 B
    _Float16* v16  = (_Float16*)(ob + 50331648 + 12582912);   // 12,582,912 B
    float*    out  = (float*)d_out;

    // 1) casts
    cast_f32_f16<<<12288, 256, 0, stream>>>(xq,  xq16,  3145728);  // 25.2M elems
    cast_f32_f16<<< 3072, 256, 0, stream>>>(xkv, xkv16,  786432);  //  6.3M elems
    cast4_f32_f16<<<dim3(288, 4), 256, 0, stream>>>(Wq, Wk, Wv, Wo,
                                                    Wq16, Wk16, Wv16, Wo16);
    hipMemsetAsync(kvh, 0, SZ_KVH + SZ_KSUM, stream);

    // 2) projections: k = elu1(xkv@Wk.T), v = xkv@Wv.T, q = elu1(xq@Wq.T)
    gemm_h16<true , false, false><<< 384, 256, 0, stream>>>(xkv16, Wk16, nullptr, k16);
    gemm_h16<false, false, false><<< 384, 256, 0, stream>>>(xkv16, Wv16, nullptr, v16);
    gemm_h16<true , false, false><<<1536, 256, 0, stream>>>(xq16 , Wq16, nullptr, q16);

    // 3) linear attention
    kv_reduce<<<dim3(8, 96), 256, 0, stream>>>(k16, v16, kvh, ksum);
    attn_kernel<<<dim3(12, 256), 256, 0, stream>>>(q16, kvh, ksum);

    // 4) out = attn @ Wo.T + bo  (fp32 output)
    gemm_h16<false, true , true ><<<1536, 256, 0, stream>>>(q16, Wo16, bo, out);
}

// Round 4
// 230.636 us; speedup vs baseline: 1.4629x; 1.1004x over previous
//
#include <hip/hip_runtime.h>

typedef _Float16 half8_t __attribute__((ext_vector_type(8)));
typedef _Float16 half4_t __attribute__((ext_vector_type(4)));
typedef float    float4_t __attribute__((ext_vector_type(4)));

#define DIM 768

// async global->LDS, 16B per lane; LDS dest is wave-uniform base + lane*16
#define GLOAD16(g, l) __builtin_amdgcn_global_load_lds(                        \
    (const __attribute__((address_space(1))) void*)(g),                        \
    (__attribute__((address_space(3))) void*)(l), 16, 0, 0)

#define MFMA16(a, b, c) __builtin_amdgcn_mfma_f32_16x16x32_f16((a), (b), (c), 0, 0, 0)

// ---------------------------------------------------------------------------
// cast helpers
// ---------------------------------------------------------------------------
__global__ __launch_bounds__(256) void cast_f32_f16(const float* __restrict__ s,
                                                    _Float16* __restrict__ d, int n8)
{
    int i = blockIdx.x * 256 + threadIdx.x;
    if (i < n8) {
        float4_t f0 = *(const float4_t*)&s[(size_t)i * 8];
        float4_t f1 = *(const float4_t*)&s[(size_t)i * 8 + 4];
        half8_t h;
        #pragma unroll
        for (int e = 0; e < 4; ++e) { h[e] = (_Float16)f0[e]; h[e + 4] = (_Float16)f1[e]; }
        *(half8_t*)&d[(size_t)i * 8] = h;
    }
}

__global__ __launch_bounds__(256) void cast4_f32_f16(
    const float* __restrict__ s0, const float* __restrict__ s1,
    const float* __restrict__ s2, const float* __restrict__ s3,
    _Float16* __restrict__ d0, _Float16* __restrict__ d1,
    _Float16* __restrict__ d2, _Float16* __restrict__ d3)
{
    const float* s; _Float16* d;
    switch (blockIdx.y) {
        case 0: s = s0; d = d0; break;
        case 1: s = s1; d = d1; break;
        case 2: s = s2; d = d2; break;
        default: s = s3; d = d3; break;
    }
    int i = blockIdx.x * 256 + threadIdx.x;
    float4_t f0 = *(const float4_t*)&s[(size_t)i * 8];
    float4_t f1 = *(const float4_t*)&s[(size_t)i * 8 + 4];
    half8_t h;
    #pragma unroll
    for (int e = 0; e < 4; ++e) { h[e] = (_Float16)f0[e]; h[e + 4] = (_Float16)f1[e]; }
    *(half8_t*)&d[(size_t)i * 8] = h;
}

// ---------------------------------------------------------------------------
// Phased fp16 NT GEMM (T1+T2+T3+T4+T5): out[r][c] = op( sum_k A[r][k]*W[c][k] )
// Tile 256x128, BK=64, 512 threads = 8 waves (2M x 4N), per-wave C 128x32.
// 3 LDS slots (48KB each = A 256x64 + B 128x64 fp16, 144KB total).
// Pipeline: compute tile t from slot t%3 while staging tile t+2 into (t+2)%3
// -> overwrite-free by construction; boundary s_waitcnt vmcnt(6), never 0
// until the tail. 2 phases/tile, 16 MFMA each, setprio around MFMA cluster.
// T2: granule swizzle gphys = glog ^ (row&7) on both tiles (16B granules),
// realized as inverse-swizzled GLOBAL source + swizzled ds_read (linear LDS
// dest, as global_load_lds requires).
// grid = (M/256)*6 blocks, col-fastest, XCD-bijective swizzle (nwg%8==0).
// ---------------------------------------------------------------------------
template<bool ELU, bool BIAS, bool OUT_F32>
__global__ __launch_bounds__(512) void gemm256(const _Float16* __restrict__ A,
                                               const _Float16* __restrict__ W,
                                               const float* __restrict__ bias,
                                               void* __restrict__ Ov)
{
    __shared__ __align__(16) _Float16 lds[3 * 24576];   // 147456 B

    const int nwg = gridDim.x;
    const int cpx = nwg >> 3;                     // nwg % 8 == 0
    const int bid = (blockIdx.x & 7) * cpx + (blockIdx.x >> 3);
    const int brow = bid / 6, bcol = bid - brow * 6;
    const int row0 = brow * 256, col0 = bcol * 128;

    const int tid  = threadIdx.x;
    const int wid  = tid >> 6, lane = tid & 63;
    const int wr   = wid >> 2;            // 0..1 : row half (128 rows)
    const int wc   = wid & 3;             // 0..3 : col quarter (32 cols)
    const int lr   = lane & 15;
    const int lkg  = lane >> 4;           // 0..3
    const int x    = lr & 7;              // swizzle key for reads

    // ---- staging map: call j covers 64 rows; thread -> (row, granule) ----
    // row = j*64 + wid*8 + (lane>>3); physical granule = lane&7;
    // logical granule = (lane&7) ^ (row&7) = (lane&7) ^ (lane>>3).
    const int  srow = wid * 8 + (lane >> 3);
    const int  sg   = ((lane & 7) ^ (lane >> 3)) * 8;   // halves
    const _Float16* Ast = A + (size_t)(row0 + srow) * DIM + sg;
    const _Float16* Bst = W + (size_t)(col0 + srow) * DIM + sg;

#define LDSA(s) (&lds[(s) * 24576])
#define LDSB(s) (&lds[(s) * 24576 + 16384])
#define STAGE_A(t, s, j) GLOAD16(Ast + (size_t)(t) * 64 + (size_t)(j) * 64 * DIM, \
                                 LDSA(s) + (j) * 4096 + wid * 512)
#define STAGE_B(t, s, j) GLOAD16(Bst + (size_t)(t) * 64 + (size_t)(j) * 64 * DIM, \
                                 LDSB(s) + (j) * 4096 + wid * 512)

    // ---- frag read bases (half indices), swizzled granule per kk ----
    const int ard = (wr * 128 + lr) * 64;
    const int brd = (wc * 32 + lr) * 64;
    const int g0  = (lkg ^ x) * 8;        // kk = 0
    const int g1  = g0 ^ 32;              // kk = 1 (granule ^ 4)

    float4_t acc[8][2] = {};

    // ---- prologue: tile0 -> slot0, tile1 -> slot1 ----
    STAGE_A(0, 0, 0); STAGE_A(0, 0, 1); STAGE_A(0, 0, 2); STAGE_A(0, 0, 3);
    STAGE_B(0, 0, 0); STAGE_B(0, 0, 1);
    STAGE_A(1, 1, 0); STAGE_A(1, 1, 1); STAGE_A(1, 1, 2); STAGE_A(1, 1, 3);
    STAGE_B(1, 1, 0); STAGE_B(1, 1, 1);
    asm volatile("s_waitcnt vmcnt(6)" ::: "memory");   // tile0 landed
    __builtin_amdgcn_s_barrier();

    int s = 0, s2 = 2;
    for (int t = 0; t < 12; ++t) {
        const _Float16* Asl = LDSA(s);
        const _Float16* Bsl = LDSB(s);
        const bool pf = (t < 10);

        // ================= phase 0 : mi 0..3 =================
        half8_t bf[2][2];
        bf[0][0] = *(const half8_t*)&Bsl[brd + g0];
        bf[0][1] = *(const half8_t*)&Bsl[brd + g1];
        bf[1][0] = *(const half8_t*)&Bsl[brd + 1024 + g0];
        bf[1][1] = *(const half8_t*)&Bsl[brd + 1024 + g1];
        half8_t af0[4][2];
        #pragma unroll
        for (int i = 0; i < 4; ++i) {
            af0[i][0] = *(const half8_t*)&Asl[ard + i * 1024 + g0];
            af0[i][1] = *(const half8_t*)&Asl[ard + i * 1024 + g1];
        }
        if (pf) { STAGE_A(t + 2, s2, 0); STAGE_A(t + 2, s2, 1); STAGE_A(t + 2, s2, 2); }
        __builtin_amdgcn_s_barrier();
        asm volatile("s_waitcnt lgkmcnt(0)" ::: "memory");
        __builtin_amdgcn_sched_barrier(0);
        __builtin_amdgcn_s_setprio(1);
        #pragma unroll
        for (int i = 0; i < 4; ++i)
            #pragma unroll
            for (int ni = 0; ni < 2; ++ni) {
                acc[i][ni] = MFMA16(af0[i][0], bf[ni][0], acc[i][ni]);
                acc[i][ni] = MFMA16(af0[i][1], bf[ni][1], acc[i][ni]);
            }
        __builtin_amdgcn_s_setprio(0);
        __builtin_amdgcn_sched_barrier(0);
        __builtin_amdgcn_s_barrier();

        // ================= phase 1 : mi 4..7 =================
        half8_t af1[4][2];
        #pragma unroll
        for (int i = 0; i < 4; ++i) {
            af1[i][0] = *(const half8_t*)&Asl[ard + 4096 + i * 1024 + g0];
            af1[i][1] = *(const half8_t*)&Asl[ard + 4096 + i * 1024 + g1];
        }
        if (pf) { STAGE_A(t + 2, s2, 3); STAGE_B(t + 2, s2, 0); STAGE_B(t + 2, s2, 1); }
        __builtin_amdgcn_s_barrier();
        asm volatile("s_waitcnt lgkmcnt(0)" ::: "memory");
        __builtin_amdgcn_sched_barrier(0);
        __builtin_amdgcn_s_setprio(1);
        #pragma unroll
        for (int i = 0; i < 4; ++i)
            #pragma unroll
            for (int ni = 0; ni < 2; ++ni) {
                acc[4 + i][ni] = MFMA16(af1[i][0], bf[ni][0], acc[4 + i][ni]);
                acc[4 + i][ni] = MFMA16(af1[i][1], bf[ni][1], acc[4 + i][ni]);
            }
        __builtin_amdgcn_s_setprio(0);
        __builtin_amdgcn_sched_barrier(0);

        // ---- tile boundary: counted vmcnt (T4), full drain only at tail ----
        if (t < 11) {
            if (pf) asm volatile("s_waitcnt vmcnt(6)" ::: "memory");
            else    asm volatile("s_waitcnt vmcnt(0)" ::: "memory");
            __builtin_amdgcn_s_barrier();
        }
        s  = (s  == 2) ? 0 : s  + 1;
        s2 = (s2 == 2) ? 0 : s2 + 1;
    }

    // ---- epilogue: C/D layout col = lane&15, row = lkg*4 + e ----
    #pragma unroll
    for (int mi = 0; mi < 8; ++mi) {
        #pragma unroll
        for (int ni = 0; ni < 2; ++ni) {
            #pragma unroll
            for (int e = 0; e < 4; ++e) {
                int r = row0 + wr * 128 + mi * 16 + lkg * 4 + e;
                int c = col0 + wc * 32 + ni * 16 + lr;
                float v = acc[mi][ni][e];
                if (ELU) v = (v > 0.0f) ? (v + 1.0f) : __expf(v);  // elu(x)+1
                if (BIAS) v += bias[c];
                if (OUT_F32) ((float*)Ov)[(size_t)r * DIM + c] = v;
                else         ((_Float16*)Ov)[(size_t)r * DIM + c] = (_Float16)v;
            }
        }
    }
#undef LDSA
#undef LDSB
#undef STAGE_A
#undef STAGE_B
}

// ---------------------------------------------------------------------------
// kv_reduce: per (b,h): kvh[e][d] = sum_n v[n,e]*k[n,d];  ksum[d] = sum_n k[n,d]
// ---------------------------------------------------------------------------
__global__ __launch_bounds__(256) void kv_reduce(const _Float16* __restrict__ k16,
                                                 const _Float16* __restrict__ v16,
                                                 float* __restrict__ kvh,
                                                 float* __restrict__ ksum)
{
    __shared__ __align__(16) _Float16 K[128][64];
    __shared__ __align__(16) _Float16 V[128][64];
    const int chunk = blockIdx.x;   // 0..7
    const int bh    = blockIdx.y;   // 0..95
    const int b = bh / 12, h = bh % 12;
    const int tid = threadIdx.x;

    const size_t base = ((size_t)b * 1024 + (size_t)chunk * 128) * DIM + h * 64;
    #pragma unroll
    for (int j = 0; j < 4; ++j) {
        int idx = j * 256 + tid;
        int r = idx >> 3, c = (idx & 7) * 8;
        *(half8_t*)&K[r][c] = *(const half8_t*)&k16[base + (size_t)r * DIM + c];
        *(half8_t*)&V[r][c] = *(const half8_t*)&v16[base + (size_t)r * DIM + c];
    }
    __syncthreads();

    const int d0 = (tid & 15) * 4;
    const int e0 = (tid >> 4) * 4;
    float acc[4][4] = {};
    #pragma unroll 4
    for (int n = 0; n < 128; ++n) {
        half4_t kd = *(const half4_t*)&K[n][d0];
        half4_t ve = *(const half4_t*)&V[n][e0];
        #pragma unroll
        for (int i = 0; i < 4; ++i)
            #pragma unroll
            for (int j = 0; j < 4; ++j)
                acc[i][j] += (float)ve[i] * (float)kd[j];
    }
    float* kvp = kvh + (size_t)bh * 64 * 64;
    #pragma unroll
    for (int i = 0; i < 4; ++i)
        #pragma unroll
        for (int j = 0; j < 4; ++j)
            atomicAdd(&kvp[(e0 + i) * 64 + d0 + j], acc[i][j]);

    if (tid < 64) {
        float s = 0.0f;
        for (int n = 0; n < 128; ++n) s += (float)K[n][tid];
        atomicAdd(&ksum[bh * 64 + tid], s);
    }
}

// ---------------------------------------------------------------------------
// attn: z = 1/(q . ksum + 1e-6); attn = (q @ kv) * z   (in-place on q16)
// ---------------------------------------------------------------------------
__global__ __launch_bounds__(256) void attn_kernel(_Float16* __restrict__ q16,
                                                   const float* __restrict__ kvh,
                                                   const float* __restrict__ ksum)
{
    __shared__ __align__(16) _Float16 Q[128][72];
    __shared__ __align__(16) _Float16 Bv[64][72];
    __shared__ float S[64];
    __shared__ float Z[128];

    const int h    = blockIdx.x;        // 0..11
    const int rb   = blockIdx.y;        // 0..255
    const int row0 = rb * 128;
    const int b    = row0 >> 12;
    const int bh   = b * 12 + h;
    const int tid  = threadIdx.x;

    #pragma unroll
    for (int j = 0; j < 4; ++j) {
        int idx = j * 256 + tid;
        int r = idx >> 3, c = (idx & 7) * 8;
        *(half8_t*)&Q[r][c] =
            *(const half8_t*)&q16[(size_t)(row0 + r) * DIM + h * 64 + c];
    }
    #pragma unroll
    for (int j = 0; j < 4; ++j) {
        int idx = j * 256 + tid;
        int r = idx >> 4, c = (idx & 15) * 4;
        float4_t f = *(const float4_t*)&kvh[((size_t)bh * 64 + r) * 64 + c];
        half4_t hh;
        #pragma unroll
        for (int e = 0; e < 4; ++e) hh[e] = (_Float16)f[e];
        *(half4_t*)&Bv[r][c] = hh;
    }
    if (tid < 64) S[tid] = ksum[bh * 64 + tid];
    __syncthreads();

    if (tid < 128) {
        float dot = 0.0f;
        #pragma unroll 8
        for (int d = 0; d < 64; ++d) dot += (float)Q[tid][d] * S[d];
        Z[tid] = 1.0f / (dot + 1e-6f);
    }
    __syncthreads();

    const int w = tid >> 6, lane = tid & 63;
    const int lr = lane & 15, lkg = lane >> 4;
    float4_t acc[2][4] = {};
    #pragma unroll
    for (int kc = 0; kc < 2; ++kc) {
        half8_t aF[2], bF[4];
        #pragma unroll
        for (int mi = 0; mi < 2; ++mi)
            aF[mi] = *(const half8_t*)&Q[w * 32 + mi * 16 + lr][kc * 32 + lkg * 8];
        #pragma unroll
        for (int ni = 0; ni < 4; ++ni)
            bF[ni] = *(const half8_t*)&Bv[ni * 16 + lr][kc * 32 + lkg * 8];
        #pragma unroll
        for (int mi = 0; mi < 2; ++mi)
            #pragma unroll
            for (int ni = 0; ni < 4; ++ni)
                acc[mi][ni] = MFMA16(aF[mi], bF[ni], acc[mi][ni]);
    }
    #pragma unroll
    for (int mi = 0; mi < 2; ++mi) {
        #pragma unroll
        for (int ni = 0; ni < 4; ++ni) {
            #pragma unroll
            for (int e = 0; e < 4; ++e) {
                int r = w * 32 + mi * 16 + lkg * 4 + e;
                float v = acc[mi][ni][e] * Z[r];
                q16[(size_t)(row0 + r) * DIM + h * 64 + ni * 16 + lr] = (_Float16)v;
            }
        }
    }
}

// ---------------------------------------------------------------------------
extern "C" void kernel_launch(void* const* d_in, const int* in_sizes, int n_in,
                              void* d_out, int out_size, void* d_ws, size_t ws_size,
                              hipStream_t stream)
{
    const float* xq  = (const float*)d_in[0];  // [8,4096,768]
    const float* xkv = (const float*)d_in[1];  // [8,1024,768]
    const float* Wq  = (const float*)d_in[2];
    const float* Wk  = (const float*)d_in[3];
    const float* Wv  = (const float*)d_in[4];
    const float* Wo  = (const float*)d_in[5];
    const float* bo  = (const float*)d_in[6];

    // ---- workspace layout ----
    char* ws = (char*)d_ws;
    const size_t SZ_XKV16 = (size_t)8192 * 768 * 2;
    const size_t SZ_Q16   = (size_t)32768 * 768 * 2;
    const size_t SZ_W16   = (size_t)768 * 768 * 2;
    const size_t SZ_KVH   = (size_t)96 * 64 * 64 * 4;
    const size_t SZ_KSUM  = (size_t)96 * 64 * 4;

    _Float16* xkv16 = (_Float16*)(ws);
    _Float16* q16   = (_Float16*)(ws + SZ_XKV16);
    _Float16* Wq16  = (_Float16*)(ws + SZ_XKV16 + SZ_Q16);
    _Float16* Wk16  = (_Float16*)(ws + SZ_XKV16 + SZ_Q16 + SZ_W16);
    _Float16* Wv16  = (_Float16*)(ws + SZ_XKV16 + SZ_Q16 + 2 * SZ_W16);
    _Float16* Wo16  = (_Float16*)(ws + SZ_XKV16 + SZ_Q16 + 3 * SZ_W16);
    float*    kvh   = (float*)   (ws + SZ_XKV16 + SZ_Q16 + 4 * SZ_W16);
    float*    ksum  = (float*)   (ws + SZ_XKV16 + SZ_Q16 + 4 * SZ_W16 + SZ_KVH);

    // ---- d_out aliasing: xq16/k16/v16 consumed before out-proj writes ----
    char* ob = (char*)d_out;
    _Float16* xq16 = (_Float16*)(ob);
    _Float16* k16  = (_Float16*)(ob + 50331648);
    _Float16* v16  = (_Float16*)(ob + 50331648 + 12582912);
    float*    out  = (float*)d_out;

    // 1) casts
    cast_f32_f16<<<12288, 256, 0, stream>>>(xq,  xq16,  3145728);
    cast_f32_f16<<< 3072, 256, 0, stream>>>(xkv, xkv16,  786432);
    cast4_f32_f16<<<dim3(288, 4), 256, 0, stream>>>(Wq, Wk, Wv, Wo,
                                                    Wq16, Wk16, Wv16, Wo16);
    hipMemsetAsync(kvh, 0, SZ_KVH + SZ_KSUM, stream);

    // 2) projections: k = elu1(xkv@Wk.T), v = xkv@Wv.T, q = elu1(xq@Wq.T)
    gemm256<true , false, false><<< 192, 512, 0, stream>>>(xkv16, Wk16, nullptr, k16);
    gemm256<false, false, false><<< 192, 512, 0, stream>>>(xkv16, Wv16, nullptr, v16);
    gemm256<true , false, false><<< 768, 512, 0, stream>>>(xq16 , Wq16, nullptr, q16);

    // 3) linear attention
    kv_reduce<<<dim3(8, 96), 256, 0, stream>>>(k16, v16, kvh, ksum);
    attn_kernel<<<dim3(12, 256), 256, 0, stream>>>(q16, kvh, ksum);

    // 4) out = attn @ Wo.T + bo  (fp32 output)
    gemm256<false, true , true ><<< 768, 512, 0, stream>>>(q16, Wo16, bo, out);
}